// Round 1
// baseline (1441.919 us; speedup 1.0000x reference)
//
#include <hip/hip_runtime.h>

#define EPSN 1e-12f
#define NB   1024            // coarse dst buckets (dst >> 8)
#define RB   256             // rows per coarse bucket (N / NB)
#define CAP  5120            // record capacity per bucket (mean 3072 after drop)
#define CHK  4096            // edges per scatter workgroup
#define GU   16              // gathers in flight per wave in fused accum

__device__ __forceinline__ float rdlane(float v, int k) {
    return __int_as_float(__builtin_amdgcn_readlane(__float_as_int(v), k));
}
__device__ __forceinline__ float preluf(float x, float a) {
    return x >= 0.0f ? x : a * x;
}

// ---------------- K1: in_feat = feat_z @ weight  (+ anchor output branch) ---
__global__ __launch_bounds__(256) void k_transform(
    const float* __restrict__ feat, const float* __restrict__ weight,
    const float* __restrict__ bias, const float* __restrict__ prelu_a,
    float* __restrict__ in_feat, float* __restrict__ out_anchor,
    int N, int totalWaves)
{
    const int lane = threadIdx.x & 63;
    const int wid = (int)((blockIdx.x * (size_t)blockDim.x + threadIdx.x) >> 6);

    float wreg[128];
    #pragma unroll
    for (int k = 0; k < 128; ++k) wreg[k] = weight[k * 64 + lane];
    const float bj = bias[lane];
    const float a  = prelu_a[0];

    for (int row = wid; row < N; row += totalWaves) {
        const float* rp = feat + (size_t)row * 128;
        float r0 = rp[lane];
        float r1 = rp[64 + lane];
        float acc0 = 0.0f, acc1 = 0.0f;
        #pragma unroll
        for (int k = 0; k < 64; ++k) {
            acc0 = fmaf(rdlane(r0, k), wreg[k],      acc0);
            acc1 = fmaf(rdlane(r1, k), wreg[64 + k], acc1);
        }
        float acc = acc0 + acc1;

        if ((row & 3) == 0) {
            float y = preluf(acc + bj, a);
            float s = y * y;
            #pragma unroll
            for (int off = 32; off >= 1; off >>= 1) s += __shfl_xor(s, off, 64);
            float dn = fmaxf(sqrtf(s), EPSN);
            out_anchor[(size_t)(row >> 2) * 64 + lane] = y / dn;
            in_feat[(size_t)row * 64 + lane] = 0.0f;   // kept for fallback path
        } else {
            in_feat[(size_t)row * 64 + lane] = acc;
        }
    }
}

// ---------------- S1: scatter edges into fixed-capacity coarse buckets -----
// atomic-append (no count/scan pre-pass); drops zero-message edges
// (src % 4 == 0 -> in_feat row is zero). record: x = src | dst_local<<18,
// y = bits(w).
__global__ __launch_bounds__(256) void s_scatter2(
    const int* __restrict__ esrc, const int* __restrict__ edst,
    const float* __restrict__ ew, int E,
    unsigned* __restrict__ cnt, uint2* __restrict__ recs)
{
    __shared__ unsigned hist[NB];
    for (int i = threadIdx.x; i < NB; i += 256) hist[i] = 0;
    __syncthreads();
    const int base = blockIdx.x * CHK;
    int s[16], d[16]; float wv[16];
    #pragma unroll
    for (int i = 0; i < 16; ++i) {
        int idx = base + i * 256 + threadIdx.x;
        const bool ok = (idx < E);
        s[i]  = ok ? esrc[idx] : 1;
        d[i]  = ok ? edst[idx] : -1;
        wv[i] = ok ? ew[idx]   : 0.0f;
        if ((s[i] & 3) == 0) d[i] = -1;      // anchor src => message is zero
        if (d[i] >= 0) atomicAdd(&hist[((unsigned)d[i]) >> 8], 1u);
    }
    __syncthreads();
    // reserve a contiguous global range per bucket; hist becomes absolute cursor
    for (int i = threadIdx.x; i < NB; i += 256) {
        unsigned c = hist[i];
        hist[i] = c ? ((unsigned)i * CAP + atomicAdd(&cnt[i], c)) : 0u;
    }
    __syncthreads();
    #pragma unroll
    for (int i = 0; i < 16; ++i) {
        if (d[i] >= 0) {
            const unsigned b = ((unsigned)d[i]) >> 8;
            const unsigned slot = atomicAdd(&hist[b], 1u);
            if (slot < (b + 1u) * CAP) {     // overflow guard (never hits for uniform dst)
                const unsigned pack = ((unsigned)s[i]) | ((((unsigned)d[i]) & 255u) << 18);
                recs[slot] = make_uint2(pack, __float_as_uint(wv[i]));
            }
        }
    }
}

// ---------------- S2: fused per-bucket accumulate + finalize ---------------
// One workgroup per coarse bucket. h-tile (256 rows x 64 cols = 64KB) lives
// in LDS; unordered records accumulate via ds_add_f32 (lane%32 banks, 2-way
// aliasing = free). Then prelu/pool/GEMV/l2norm in-block -> h never touches
// global memory, k_finalize and the fine sort are deleted.
__global__ __launch_bounds__(256) void s_bucket(
    const float* __restrict__ in_feat, const uint2* __restrict__ recs,
    const unsigned* __restrict__ cnt,
    const float* __restrict__ bias, const float* __restrict__ prelu_a,
    const float* __restrict__ w_sub, const float* __restrict__ b_sub,
    const float* __restrict__ w_gcn, const float* __restrict__ b_gcn,
    float* __restrict__ out_sub, float* __restrict__ out_gcn)
{
    __shared__ float tile[RB * 64];          // 64 KB
    const int tid  = threadIdx.x;
    const int lane = tid & 63;
    const int wv4  = tid >> 6;               // wave 0..3
    const int b    = blockIdx.x;

    {   // zero tile: 4096 float4 / 256 threads
        const float4 z = make_float4(0.f, 0.f, 0.f, 0.f);
        float4* t4 = (float4*)tile;
        #pragma unroll
        for (int i = 0; i < 16; ++i) t4[tid + i * 256] = z;
    }
    __syncthreads();

    const unsigned n  = min(cnt[b], (unsigned)CAP);
    const uint2*   rp = recs + (size_t)b * CAP;

    for (unsigned base = (unsigned)wv4 * 64u; base < n; base += 256u) {
        const int c = (int)min(64u, n - base);
        uint2 rcd = make_uint2(0u, 0u);
        if (lane < c) rcd = rp[base + lane];             // coalesced 8B x c
        for (int j0 = 0; j0 < c; j0 += GU) {
            float v[GU], wj[GU]; int dl[GU];
            #pragma unroll
            for (int jj = 0; jj < GU; ++jj) {
                const int idx = j0 + jj;
                const int cl  = (idx < c) ? idx : (c - 1);
                const unsigned px =
                    (unsigned)__builtin_amdgcn_readlane((int)rcd.x, cl);
                const float ww =
                    __int_as_float(__builtin_amdgcn_readlane((int)rcd.y, cl));
                v[jj]  = in_feat[((size_t)(px & 0x3FFFFu) << 6) + lane];
                dl[jj] = (int)(px >> 18);
                wj[jj] = (idx < c) ? ww : 0.0f;
            }
            #pragma unroll
            for (int jj = 0; jj < GU; ++jj)
                atomicAdd(&tile[dl[jj] * 64 + lane], v[jj] * wj[jj]);
        }
    }
    __syncthreads();

    // finalize: 64 groups of 4 rows per bucket, 16 groups per wave
    float wsreg[64], wgreg[64];
    #pragma unroll
    for (int k = 0; k < 64; ++k) wsreg[k] = w_sub[lane * 64 + k];
    #pragma unroll
    for (int k = 0; k < 64; ++k) wgreg[k] = w_gcn[lane * 64 + k];
    const float bj  = bias[lane];
    const float bsj = b_sub[lane];
    const float bgj = b_gcn[lane];
    const float a   = prelu_a[0];

    for (int g = wv4; g < 64; g += 4) {
        const float* hp = tile + g * 256;
        float p0 = preluf(hp[lane]       + bj, a);
        float p1 = preluf(hp[64  + lane] + bj, a);
        float p2 = preluf(hp[128 + lane] + bj, a);
        float p3 = preluf(hp[192 + lane] + bj, a);
        float pool = (p0 + p1 + p2 + p3) * 0.25f;
        float gcn  = p0;

        float as = bsj, ag = bgj;
        #pragma unroll
        for (int k = 0; k < 64; ++k) {
            as = fmaf(rdlane(pool, k), wsreg[k], as);
            ag = fmaf(rdlane(gcn,  k), wgreg[k], ag);
        }
        float ss = as * as, sg = ag * ag;
        #pragma unroll
        for (int off = 32; off >= 1; off >>= 1) {
            ss += __shfl_xor(ss, off, 64);
            sg += __shfl_xor(sg, off, 64);
        }
        const size_t go = (size_t)(b * 64 + g) * 64 + lane;
        out_sub[go] = as / fmaxf(sqrtf(ss), EPSN);
        out_gcn[go] = ag / fmaxf(sqrtf(sg), EPSN);
    }
}

// ---------------- fallback K2 (atomic scatter) ----------------------------
#define K2_U 8
__global__ __launch_bounds__(256) void k_edges(
    const float* __restrict__ in_feat, const int* __restrict__ esrc,
    const int* __restrict__ edst, const float* __restrict__ ew,
    float* __restrict__ h, int E, int totalWaves)
{
    const int lane = threadIdx.x & 63;
    int wid = (int)((blockIdx.x * (size_t)blockDim.x + threadIdx.x) >> 6);
    wid = __builtin_amdgcn_readfirstlane(wid);
    const int chunk = (E + totalWaves - 1) / totalWaves;
    int e0 = wid * chunk;
    int e1 = min(e0 + chunk, E);
    for (int base = e0; base < e1; base += K2_U) {
        const int nb = min(K2_U, e1 - base);
        int s[K2_U], d[K2_U]; float w[K2_U];
        #pragma unroll
        for (int j = 0; j < K2_U; ++j) {
            int idx = base + ((j < nb) ? j : 0);
            s[j] = esrc[idx]; d[j] = edst[idx]; w[j] = ew[idx];
        }
        float v[K2_U];
        #pragma unroll
        for (int j = 0; j < K2_U; ++j)
            v[j] = in_feat[((size_t)s[j] << 6) + lane];
        #pragma unroll
        for (int j = 0; j < K2_U; ++j)
            if (j < nb) atomicAdd(h + ((size_t)d[j] << 6) + lane, v[j] * w[j]);
    }
}

// ---------------- fallback K3: activation + pool + two GEMVs + l2norm -----
__global__ __launch_bounds__(256) void k_finalize(
    const float* __restrict__ h, const float* __restrict__ bias,
    const float* __restrict__ prelu_a,
    const float* __restrict__ w_sub, const float* __restrict__ b_sub,
    const float* __restrict__ w_gcn, const float* __restrict__ b_gcn,
    float* __restrict__ out_sub, float* __restrict__ out_gcn,
    int G, int totalWaves)
{
    const int lane = threadIdx.x & 63;
    const int wid = (int)((blockIdx.x * (size_t)blockDim.x + threadIdx.x) >> 6);

    float wsreg[64], wgreg[64];
    #pragma unroll
    for (int k = 0; k < 64; ++k) wsreg[k] = w_sub[lane * 64 + k];
    #pragma unroll
    for (int k = 0; k < 64; ++k) wgreg[k] = w_gcn[lane * 64 + k];
    const float bj  = bias[lane];
    const float bsj = b_sub[lane];
    const float bgj = b_gcn[lane];
    const float a   = prelu_a[0];

    for (int g = wid; g < G; g += totalWaves) {
        const float* hp = h + (size_t)g * 256;
        float p0 = preluf(hp[lane]       + bj, a);
        float p1 = preluf(hp[64  + lane] + bj, a);
        float p2 = preluf(hp[128 + lane] + bj, a);
        float p3 = preluf(hp[192 + lane] + bj, a);
        float pool = (p0 + p1 + p2 + p3) * 0.25f;
        float gcn  = p0;

        float as = bsj, ag = bgj;
        #pragma unroll
        for (int k = 0; k < 64; ++k) {
            as = fmaf(rdlane(pool, k), wsreg[k], as);
            ag = fmaf(rdlane(gcn,  k), wgreg[k], ag);
        }
        float ss = as * as, sg = ag * ag;
        #pragma unroll
        for (int off = 32; off >= 1; off >>= 1) {
            ss += __shfl_xor(ss, off, 64);
            sg += __shfl_xor(sg, off, 64);
        }
        out_sub[(size_t)g * 64 + lane] = as / fmaxf(sqrtf(ss), EPSN);
        out_gcn[(size_t)g * 64 + lane] = ag / fmaxf(sqrtf(sg), EPSN);
    }
}

extern "C" void kernel_launch(void* const* d_in, const int* in_sizes, int n_in,
                              void* d_out, int out_size, void* d_ws, size_t ws_size,
                              hipStream_t stream)
{
    const float* feat    = (const float*)d_in[0];
    const int*   esrc    = (const int*)  d_in[1];
    const int*   edst    = (const int*)  d_in[2];
    const float* ew      = (const float*)d_in[3];
    const float* weight  = (const float*)d_in[4];
    const float* bias    = (const float*)d_in[5];
    const float* prelu_a = (const float*)d_in[6];
    const float* w_sub   = (const float*)d_in[7];
    const float* b_sub   = (const float*)d_in[8];
    const float* w_gcn   = (const float*)d_in[9];
    const float* b_gcn   = (const float*)d_in[10];

    const int N = in_sizes[0] / 128;
    const int E = in_sizes[1];
    const int G = N / 4;

    // ws layout (fused path):
    //   [0, 67.1MB)        in_feat
    //   [67.1, 109.0MB)    recs (NB * CAP records, 8B each)
    //   tail               cnt[NB]
    // fallback path overlays h at +67.1MB (recs region unused there).
    char* wsb = (char*)d_ws;
    float*    in_feat = (float*)wsb;
    uint2*    recs    = (uint2*)(wsb + (size_t)N * 64 * 4);
    unsigned* cnt     = (unsigned*)(wsb + (size_t)N * 64 * 4 + (size_t)NB * CAP * 8);
    float*    h       = (float*)(wsb + (size_t)N * 64 * 4);
    const size_t ws_need_fused = (size_t)N * 64 * 4 + (size_t)NB * CAP * 8 + NB * 4;
    const size_t ws_need_fall  = (size_t)2 * N * 64 * 4;

    float* out        = (float*)d_out;
    float* out_sub    = out;
    float* out_anchor = out + (size_t)G * 64;
    float* out_gcn    = out + (size_t)2 * G * 64;

    const bool fused_path = (N == NB * RB) && (ws_size >= ws_need_fused);

    {   // K1
        const int blocks = 2048, tw = blocks * 4;
        k_transform<<<blocks, 256, 0, stream>>>(feat, weight, bias, prelu_a,
                                                in_feat, out_anchor, N, tw);
    }

    if (fused_path) {
        hipMemsetAsync(cnt, 0, NB * sizeof(unsigned), stream);
        const int nwg = (E + CHK - 1) / CHK;
        s_scatter2<<<nwg, 256, 0, stream>>>(esrc, edst, ew, E, cnt, recs);
        s_bucket  <<<NB, 256, 0, stream>>>(in_feat, recs, cnt, bias, prelu_a,
                                           w_sub, b_sub, w_gcn, b_gcn,
                                           out_sub, out_gcn);
    } else if (ws_size >= ws_need_fall) {
        hipMemsetAsync(h, 0, (size_t)N * 64 * sizeof(float), stream);
        const int blocks = 2048, tw = blocks * 4;
        k_edges<<<blocks, 256, 0, stream>>>(in_feat, esrc, edst, ew, h, E, tw);
        const int fblocks = 4096, ftw = fblocks * 4;
        k_finalize<<<fblocks, 256, 0, stream>>>(h, bias, prelu_a, w_sub, b_sub,
                                                w_gcn, b_gcn, out_sub, out_gcn, G, ftw);
    }
}

// Round 2
// 734.793 us; speedup vs baseline: 1.9623x; 1.9623x over previous
//
#include <hip/hip_runtime.h>

#define EPSN 1e-12f
#define NB   1024            // coarse dst buckets (dst >> 8)
#define RB   256             // rows per coarse bucket (N / NB)
#define CHK  4096            // edges per count/scatter workgroup
#define NWGMAX 2048          // scanA supports up to 2048 edge blocks (PER=8)
#define GU   8               // gathers in flight per wave in accumulate

__device__ __forceinline__ float rdlane(float v, int k) {
    return __int_as_float(__builtin_amdgcn_readlane(__float_as_int(v), k));
}
__device__ __forceinline__ float preluf(float x, float a) {
    return x >= 0.0f ? x : a * x;
}

// ---------------- K1: in_feat = feat_z @ weight  (+ anchor output branch) ---
__global__ __launch_bounds__(256) void k_transform(
    const float* __restrict__ feat, const float* __restrict__ weight,
    const float* __restrict__ bias, const float* __restrict__ prelu_a,
    float* __restrict__ in_feat, float* __restrict__ out_anchor,
    int N, int totalWaves)
{
    const int lane = threadIdx.x & 63;
    const int wid = (int)((blockIdx.x * (size_t)blockDim.x + threadIdx.x) >> 6);

    float wreg[128];
    #pragma unroll
    for (int k = 0; k < 128; ++k) wreg[k] = weight[k * 64 + lane];
    const float bj = bias[lane];
    const float a  = prelu_a[0];

    for (int row = wid; row < N; row += totalWaves) {
        const float* rp = feat + (size_t)row * 128;
        float r0 = rp[lane];
        float r1 = rp[64 + lane];
        float acc0 = 0.0f, acc1 = 0.0f;
        #pragma unroll
        for (int k = 0; k < 64; ++k) {
            acc0 = fmaf(rdlane(r0, k), wreg[k],      acc0);
            acc1 = fmaf(rdlane(r1, k), wreg[64 + k], acc1);
        }
        float acc = acc0 + acc1;

        if ((row & 3) == 0) {
            float y = preluf(acc + bj, a);
            float s = y * y;
            #pragma unroll
            for (int off = 32; off >= 1; off >>= 1) s += __shfl_xor(s, off, 64);
            float dn = fmaxf(sqrtf(s), EPSN);
            out_anchor[(size_t)(row >> 2) * 64 + lane] = y / dn;
            in_feat[(size_t)row * 64 + lane] = 0.0f;   // needed by fallback path
        } else {
            in_feat[(size_t)row * 64 + lane] = acc;
        }
    }
}

// ---------------- S1: per-block bucket histograms (NO global atomics) ------
// drops zero-message edges (src % 4 == 0 -> in_feat row is zero)
__global__ __launch_bounds__(256) void s_count2(
    const int* __restrict__ esrc, const int* __restrict__ edst, int E,
    unsigned* __restrict__ C)
{
    __shared__ unsigned hist[NB];
    for (int i = threadIdx.x; i < NB; i += 256) hist[i] = 0;
    __syncthreads();
    const int base = blockIdx.x * CHK;
    #pragma unroll
    for (int i = 0; i < 16; ++i) {
        int idx = base + i * 256 + threadIdx.x;
        if (idx < E) {
            int s = esrc[idx];
            if ((s & 3) != 0)
                atomicAdd(&hist[((unsigned)edst[idx]) >> 8], 1u);
        }
    }
    __syncthreads();
    for (int i = threadIdx.x; i < NB; i += 256)
        C[(size_t)blockIdx.x * NB + i] = hist[i];
}

// ---------------- S2a: per-bucket exclusive scan over blocks ---------------
// block i scans C[blk][i] over blk; writes PT[blk][i] (excl prefix) + T[i].
__global__ __launch_bounds__(256) void s_scanA(
    const unsigned* __restrict__ C, unsigned* __restrict__ PT,
    unsigned* __restrict__ T, int nwg)
{
    __shared__ unsigned ssum[256];
    const int i = blockIdx.x;
    const int t = threadIdx.x;
    unsigned vals[8];
    unsigned run = 0;
    #pragma unroll
    for (int p = 0; p < 8; ++p) {
        const int blk = t * 8 + p;
        const unsigned v = (blk < nwg) ? C[(size_t)blk * NB + i] : 0u;
        vals[p] = run;
        run += v;
    }
    ssum[t] = run;
    __syncthreads();
    for (int off = 1; off < 256; off <<= 1) {
        unsigned x = (t >= off) ? ssum[t - off] : 0u;
        __syncthreads();
        ssum[t] += x;
        __syncthreads();
    }
    const unsigned texcl = ssum[t] - run;
    #pragma unroll
    for (int p = 0; p < 8; ++p) {
        const int blk = t * 8 + p;
        if (blk < nwg) PT[(size_t)blk * NB + i] = texcl + vals[p];
    }
    if (t == 255) T[i] = ssum[255];
}

// ---------------- S2b: exclusive scan over NB bucket totals ----------------
__global__ __launch_bounds__(1024) void s_scanB(
    const unsigned* __restrict__ T, unsigned* __restrict__ basep,
    unsigned* __restrict__ rs, int N)
{
    __shared__ unsigned sc[NB];
    const int t = threadIdx.x;
    unsigned my = T[t];
    sc[t] = my;
    __syncthreads();
    for (int off = 1; off < NB; off <<= 1) {
        unsigned a = (t >= off) ? sc[t - off] : 0u;
        __syncthreads();
        sc[t] += a;
        __syncthreads();
    }
    basep[t] = sc[t] - my;
    if (t == NB - 1) { basep[NB] = sc[t]; rs[N] = sc[t]; }
}

// ---------------- S3: scatter into coarse-sorted records (LDS cursors only)
__global__ __launch_bounds__(256) void s_scatter3(
    const int* __restrict__ esrc, const int* __restrict__ edst,
    const float* __restrict__ ew, int E,
    const unsigned* __restrict__ basep, const unsigned* __restrict__ PT,
    uint2* __restrict__ recs)
{
    __shared__ unsigned cur[NB];
    const int blk = blockIdx.x;
    for (int i = threadIdx.x; i < NB; i += 256)
        cur[i] = basep[i] + PT[(size_t)blk * NB + i];
    __syncthreads();
    const int base = blk * CHK;
    int s[16], d[16]; float wv[16];
    #pragma unroll
    for (int i = 0; i < 16; ++i) {
        int idx = base + i * 256 + threadIdx.x;
        const bool ok = (idx < E);
        s[i]  = ok ? esrc[idx] : 0;
        d[i]  = ok ? edst[idx] : 0;
        wv[i] = ok ? ew[idx]   : 0.0f;
        if (!ok || (s[i] & 3) == 0) d[i] = -1;   // pad or anchor-src: skip
    }
    #pragma unroll
    for (int i = 0; i < 16; ++i) {
        if (d[i] >= 0) {
            const unsigned slot = atomicAdd(&cur[((unsigned)d[i]) >> 8], 1u);
            const unsigned pack =
                ((unsigned)s[i]) | ((((unsigned)d[i]) & 255u) << 18);
            recs[slot] = make_uint2(pack, __float_as_uint(wv[i]));
        }
    }
}

// ---------------- S4: per-bucket fine sort (by dst_local) ------------------
__global__ __launch_bounds__(256) void s_sortfine(
    const uint2* __restrict__ recs, const unsigned* __restrict__ basep,
    uint2* __restrict__ recf, unsigned* __restrict__ rs)
{
    __shared__ unsigned hist[RB], sc[RB], cur[RB];
    const int t = threadIdx.x;
    const int b = blockIdx.x;
    const unsigned start = basep[b], end = basep[b + 1];
    hist[t] = 0;
    __syncthreads();
    for (unsigned i = start + t; i < end; i += 256)
        atomicAdd(&hist[recs[i].x >> 18], 1u);
    __syncthreads();
    sc[t] = hist[t];
    __syncthreads();
    for (int off = 1; off < RB; off <<= 1) {
        unsigned v = (t >= off) ? sc[t - off] : 0u;
        __syncthreads();
        sc[t] += v;
        __syncthreads();
    }
    const unsigned excl = sc[t] - hist[t];
    cur[t] = start + excl;
    rs[b * RB + t] = start + excl;
    __syncthreads();
    for (unsigned i = start + t; i < end; i += 256) {
        uint2 r = recs[i];
        unsigned slot = atomicAdd(&cur[r.x >> 18], 1u);
        recf[slot] = make_uint2(r.x & 0x3FFFFu, r.y);
    }
}

// ---------------- S5: fused accumulate + finalize --------------------------
// one wave per 4-row group: register accumulation (r0's proven high-occupancy
// gather structure), then prelu/pool/GEMV/l2norm in-place. h never exists.
__global__ __launch_bounds__(256) void s_accfin(
    const float* __restrict__ in_feat, const uint2* __restrict__ recf,
    const unsigned* __restrict__ rs,
    const float* __restrict__ bias, const float* __restrict__ prelu_a,
    const float* __restrict__ w_sub, const float* __restrict__ b_sub,
    const float* __restrict__ w_gcn, const float* __restrict__ b_gcn,
    float* __restrict__ out_sub, float* __restrict__ out_gcn,
    int G, int totalWaves)
{
    __shared__ float wTs[64 * 64], wTg[64 * 64];   // transposed weights, 32 KB
    const int tid  = threadIdx.x;
    const int lane = tid & 63;

    for (int i = tid; i < 4096; i += 256) {
        const int j = i >> 6, k = i & 63;          // w[j][k] -> wT[k][j]
        wTs[k * 64 + j] = w_sub[i];
        wTg[k * 64 + j] = w_gcn[i];
    }
    __syncthreads();

    const float bj  = bias[lane];
    const float bsj = b_sub[lane];
    const float bgj = b_gcn[lane];
    const float a   = prelu_a[0];

    const int wid = (int)((blockIdx.x * (size_t)blockDim.x + tid) >> 6);

    for (int g = wid; g < G; g += totalWaves) {
        float acc[4];
        #pragma unroll
        for (int r = 0; r < 4; ++r) {
            const unsigned s = rs[4 * g + r], e = rs[4 * g + r + 1];
            float ac = 0.0f;
            unsigned done = s;
            while (done < e) {
                const int c = (int)min(64u, e - done);
                uint2 rcd = make_uint2(0u, 0u);
                if (lane < c) rcd = recf[done + lane];   // coalesced 8B x c
                for (int j0 = 0; j0 < c; j0 += GU) {
                    float v[GU], wj[GU];
                    #pragma unroll
                    for (int jj = 0; jj < GU; ++jj) {
                        const int idx = j0 + jj;
                        const int cl  = (idx < c) ? idx : (c - 1);
                        const unsigned sidx =
                            (unsigned)__builtin_amdgcn_readlane((int)rcd.x, cl);
                        const float wv =
                            __int_as_float(__builtin_amdgcn_readlane((int)rcd.y, cl));
                        v[jj]  = in_feat[((size_t)sidx << 6) + lane];
                        wj[jj] = (idx < c) ? wv : 0.0f;
                    }
                    #pragma unroll
                    for (int jj = 0; jj < GU; ++jj) ac = fmaf(v[jj], wj[jj], ac);
                }
                done += (unsigned)c;
            }
            acc[r] = ac;
        }

        const float p0 = preluf(acc[0] + bj, a);
        const float p1 = preluf(acc[1] + bj, a);
        const float p2 = preluf(acc[2] + bj, a);
        const float p3 = preluf(acc[3] + bj, a);
        const float pool = (p0 + p1 + p2 + p3) * 0.25f;
        const float gcn  = p0;

        float as = bsj, ag = bgj;
        #pragma unroll
        for (int k = 0; k < 64; ++k) {
            as = fmaf(rdlane(pool, k), wTs[k * 64 + lane], as);
            ag = fmaf(rdlane(gcn,  k), wTg[k * 64 + lane], ag);
        }
        float ss = as * as, sg = ag * ag;
        #pragma unroll
        for (int off = 32; off >= 1; off >>= 1) {
            ss += __shfl_xor(ss, off, 64);
            sg += __shfl_xor(sg, off, 64);
        }
        const size_t go = (size_t)g * 64 + lane;
        out_sub[go] = as / fmaxf(sqrtf(ss), EPSN);
        out_gcn[go] = ag / fmaxf(sqrtf(sg), EPSN);
    }
}

// ---------------- fallback K2 (atomic scatter) ----------------------------
#define K2_U 8
__global__ __launch_bounds__(256) void k_edges(
    const float* __restrict__ in_feat, const int* __restrict__ esrc,
    const int* __restrict__ edst, const float* __restrict__ ew,
    float* __restrict__ h, int E, int totalWaves)
{
    const int lane = threadIdx.x & 63;
    int wid = (int)((blockIdx.x * (size_t)blockDim.x + threadIdx.x) >> 6);
    wid = __builtin_amdgcn_readfirstlane(wid);
    const int chunk = (E + totalWaves - 1) / totalWaves;
    int e0 = wid * chunk;
    int e1 = min(e0 + chunk, E);
    for (int base = e0; base < e1; base += K2_U) {
        const int nb = min(K2_U, e1 - base);
        int s[K2_U], d[K2_U]; float w[K2_U];
        #pragma unroll
        for (int j = 0; j < K2_U; ++j) {
            int idx = base + ((j < nb) ? j : 0);
            s[j] = esrc[idx]; d[j] = edst[idx]; w[j] = ew[idx];
        }
        float v[K2_U];
        #pragma unroll
        for (int j = 0; j < K2_U; ++j)
            v[j] = in_feat[((size_t)s[j] << 6) + lane];
        #pragma unroll
        for (int j = 0; j < K2_U; ++j)
            if (j < nb) atomicAdd(h + ((size_t)d[j] << 6) + lane, v[j] * w[j]);
    }
}

// ---------------- fallback K3: activation + pool + GEMVs + l2norm ---------
__global__ __launch_bounds__(256) void k_finalize(
    const float* __restrict__ h, const float* __restrict__ bias,
    const float* __restrict__ prelu_a,
    const float* __restrict__ w_sub, const float* __restrict__ b_sub,
    const float* __restrict__ w_gcn, const float* __restrict__ b_gcn,
    float* __restrict__ out_sub, float* __restrict__ out_gcn,
    int G, int totalWaves)
{
    const int lane = threadIdx.x & 63;
    const int wid = (int)((blockIdx.x * (size_t)blockDim.x + threadIdx.x) >> 6);

    float wsreg[64], wgreg[64];
    #pragma unroll
    for (int k = 0; k < 64; ++k) wsreg[k] = w_sub[lane * 64 + k];
    #pragma unroll
    for (int k = 0; k < 64; ++k) wgreg[k] = w_gcn[lane * 64 + k];
    const float bj  = bias[lane];
    const float bsj = b_sub[lane];
    const float bgj = b_gcn[lane];
    const float a   = prelu_a[0];

    for (int g = wid; g < G; g += totalWaves) {
        const float* hp = h + (size_t)g * 256;
        float p0 = preluf(hp[lane]       + bj, a);
        float p1 = preluf(hp[64  + lane] + bj, a);
        float p2 = preluf(hp[128 + lane] + bj, a);
        float p3 = preluf(hp[192 + lane] + bj, a);
        float pool = (p0 + p1 + p2 + p3) * 0.25f;
        float gcn  = p0;

        float as = bsj, ag = bgj;
        #pragma unroll
        for (int k = 0; k < 64; ++k) {
            as = fmaf(rdlane(pool, k), wsreg[k], as);
            ag = fmaf(rdlane(gcn,  k), wgreg[k], ag);
        }
        float ss = as * as, sg = ag * ag;
        #pragma unroll
        for (int off = 32; off >= 1; off >>= 1) {
            ss += __shfl_xor(ss, off, 64);
            sg += __shfl_xor(sg, off, 64);
        }
        out_sub[(size_t)g * 64 + lane] = as / fmaxf(sqrtf(ss), EPSN);
        out_gcn[(size_t)g * 64 + lane] = ag / fmaxf(sqrtf(sg), EPSN);
    }
}

extern "C" void kernel_launch(void* const* d_in, const int* in_sizes, int n_in,
                              void* d_out, int out_size, void* d_ws, size_t ws_size,
                              hipStream_t stream)
{
    const float* feat    = (const float*)d_in[0];
    const int*   esrc    = (const int*)  d_in[1];
    const int*   edst    = (const int*)  d_in[2];
    const float* ew      = (const float*)d_in[3];
    const float* weight  = (const float*)d_in[4];
    const float* bias    = (const float*)d_in[5];
    const float* prelu_a = (const float*)d_in[6];
    const float* w_sub   = (const float*)d_in[7];
    const float* b_sub   = (const float*)d_in[8];
    const float* w_gcn   = (const float*)d_in[9];
    const float* b_gcn   = (const float*)d_in[10];

    const int N = in_sizes[0] / 128;
    const int E = in_sizes[1];
    const int G = N / 4;
    const int nwg = (E + CHK - 1) / CHK;

    // ws layout (sorted path; all offsets in bytes):
    //   in_feat : N*64*4                      (67.1 MB)
    //   recs    : E*8                         (33.5 MB, dead after sortfine)
    //   recf    : E*8                         (33.5 MB)
    //   C       : nwg*NB*4                    (4 MB)
    //   PT      : nwg*NB*4                    (4 MB)
    //   T       : NB*4
    //   basep   : (NB+1)*4
    //   rs      : (N+1)*4                     (1.05 MB)
    char* wsb = (char*)d_ws;
    const size_t offA  = (size_t)N * 64 * 4;
    const size_t offRf = offA  + (size_t)E * 8;
    const size_t offC  = offRf + (size_t)E * 8;
    const size_t offPT = offC  + (size_t)nwg * NB * 4;
    const size_t offT  = offPT + (size_t)nwg * NB * 4;
    const size_t offBp = offT  + (size_t)NB * 4;
    const size_t offRs = offBp + (size_t)(NB + 1) * 4;
    const size_t ws_need = offRs + (size_t)(N + 1) * 4;

    float*    in_feat = (float*)wsb;
    uint2*    recs    = (uint2*)(wsb + offA);
    uint2*    recf    = (uint2*)(wsb + offRf);
    unsigned* C       = (unsigned*)(wsb + offC);
    unsigned* PT      = (unsigned*)(wsb + offPT);
    unsigned* T       = (unsigned*)(wsb + offT);
    unsigned* basep   = (unsigned*)(wsb + offBp);
    unsigned* rs      = (unsigned*)(wsb + offRs);
    float*    h       = (float*)(wsb + offA);    // fallback overlay

    float* out        = (float*)d_out;
    float* out_sub    = out;
    float* out_anchor = out + (size_t)G * 64;
    float* out_gcn    = out + (size_t)2 * G * 64;

    const bool sorted_path =
        (N == NB * RB) && (nwg <= NWGMAX) && (ws_size >= ws_need);

    {   // K1
        const int blocks = 2048, tw = blocks * 4;
        k_transform<<<blocks, 256, 0, stream>>>(feat, weight, bias, prelu_a,
                                                in_feat, out_anchor, N, tw);
    }

    if (sorted_path) {
        s_count2  <<<nwg, 256, 0, stream>>>(esrc, edst, E, C);
        s_scanA   <<<NB, 256, 0, stream>>>(C, PT, T, nwg);
        s_scanB   <<<1, 1024, 0, stream>>>(T, basep, rs, N);
        s_scatter3<<<nwg, 256, 0, stream>>>(esrc, edst, ew, E, basep, PT, recs);
        s_sortfine<<<NB, 256, 0, stream>>>(recs, basep, recf, rs);
        {
            const int blocks = 2048, tw = blocks * 4;   // 8192 waves, 8 groups each
            s_accfin<<<blocks, 256, 0, stream>>>(in_feat, recf, rs, bias, prelu_a,
                                                 w_sub, b_sub, w_gcn, b_gcn,
                                                 out_sub, out_gcn, G, tw);
        }
    } else if (ws_size >= (size_t)2 * N * 64 * 4) {
        hipMemsetAsync(h, 0, (size_t)N * 64 * sizeof(float), stream);
        const int blocks = 2048, tw = blocks * 4;
        k_edges<<<blocks, 256, 0, stream>>>(in_feat, esrc, edst, ew, h, E, tw);
        const int fblocks = 4096, ftw = fblocks * 4;
        k_finalize<<<fblocks, 256, 0, stream>>>(h, bias, prelu_a, w_sub, b_sub,
                                                w_gcn, b_gcn, out_sub, out_gcn, G, ftw);
    }
}

// Round 3
// 635.730 us; speedup vs baseline: 2.2681x; 1.1558x over previous
//
#include <hip/hip_runtime.h>

#define EPSN 1e-12f
#define NB   1024            // coarse dst buckets (dst >> 8)
#define RB   256             // rows per coarse bucket (N / NB)
#define CHK  4096            // edges per count/scatter workgroup
#define NWGMAX 2048          // scanA supports up to 2048 edge blocks (PER=8)
#define GU   8               // gathers in flight per wave in accumulate
#define WQS  16384.0f        // weight quantization scale (14 bits)

__device__ __forceinline__ float rdlane(float v, int k) {
    return __int_as_float(__builtin_amdgcn_readlane(__float_as_int(v), k));
}
__device__ __forceinline__ float preluf(float x, float a) {
    return x >= 0.0f ? x : a * x;
}

// ---------------- K1: in_feat = feat_z @ weight  (+ anchor output branch) ---
__global__ __launch_bounds__(256) void k_transform(
    const float* __restrict__ feat, const float* __restrict__ weight,
    const float* __restrict__ bias, const float* __restrict__ prelu_a,
    float* __restrict__ in_feat, float* __restrict__ out_anchor,
    int N, int totalWaves)
{
    const int lane = threadIdx.x & 63;
    const int wid = (int)((blockIdx.x * (size_t)blockDim.x + threadIdx.x) >> 6);

    float wreg[128];
    #pragma unroll
    for (int k = 0; k < 128; ++k) wreg[k] = weight[k * 64 + lane];
    const float bj = bias[lane];
    const float a  = prelu_a[0];

    for (int row = wid; row < N; row += totalWaves) {
        const float* rp = feat + (size_t)row * 128;
        float r0 = rp[lane];
        float r1 = rp[64 + lane];
        float acc0 = 0.0f, acc1 = 0.0f;
        #pragma unroll
        for (int k = 0; k < 64; ++k) {
            acc0 = fmaf(rdlane(r0, k), wreg[k],      acc0);
            acc1 = fmaf(rdlane(r1, k), wreg[64 + k], acc1);
        }
        float acc = acc0 + acc1;

        if ((row & 3) == 0) {
            float y = preluf(acc + bj, a);
            float s = y * y;
            #pragma unroll
            for (int off = 32; off >= 1; off >>= 1) s += __shfl_xor(s, off, 64);
            float dn = fmaxf(sqrtf(s), EPSN);
            out_anchor[(size_t)(row >> 2) * 64 + lane] = y / dn;
            in_feat[(size_t)row * 64 + lane] = 0.0f;   // needed by fallback path
        } else {
            in_feat[(size_t)row * 64 + lane] = acc;
        }
    }
}

// ---------------- S1: per-block bucket histograms (NO global atomics) ------
// drops zero-message edges (src % 4 == 0 -> in_feat row is zero)
__global__ __launch_bounds__(256) void s_count2(
    const int* __restrict__ esrc, const int* __restrict__ edst, int E,
    unsigned* __restrict__ C)
{
    __shared__ unsigned hist[NB];
    for (int i = threadIdx.x; i < NB; i += 256) hist[i] = 0;
    __syncthreads();
    const int base = blockIdx.x * CHK;
    #pragma unroll
    for (int i = 0; i < 16; ++i) {
        int idx = base + i * 256 + threadIdx.x;
        if (idx < E) {
            int s = esrc[idx];
            if ((s & 3) != 0)
                atomicAdd(&hist[((unsigned)edst[idx]) >> 8], 1u);
        }
    }
    __syncthreads();
    for (int i = threadIdx.x; i < NB; i += 256)
        C[(size_t)blockIdx.x * NB + i] = hist[i];
}

// ---------------- S2a: per-bucket exclusive scan over blocks, IN PLACE -----
// block i scans C[blk][i] over blk; rewrites C[blk][i] = excl prefix; T[i]=sum
__global__ __launch_bounds__(256) void s_scanA(
    unsigned* __restrict__ C, unsigned* __restrict__ T, int nwg)
{
    __shared__ unsigned ssum[256];
    const int i = blockIdx.x;
    const int t = threadIdx.x;
    unsigned vals[8];
    unsigned run = 0;
    #pragma unroll
    for (int p = 0; p < 8; ++p) {
        const int blk = t * 8 + p;
        const unsigned v = (blk < nwg) ? C[(size_t)blk * NB + i] : 0u;
        vals[p] = run;
        run += v;
    }
    ssum[t] = run;
    __syncthreads();
    for (int off = 1; off < 256; off <<= 1) {
        unsigned x = (t >= off) ? ssum[t - off] : 0u;
        __syncthreads();
        ssum[t] += x;
        __syncthreads();
    }
    const unsigned texcl = ssum[t] - run;
    #pragma unroll
    for (int p = 0; p < 8; ++p) {
        const int blk = t * 8 + p;
        if (blk < nwg) C[(size_t)blk * NB + i] = texcl + vals[p];
    }
    if (t == 255) T[i] = ssum[255];
}

// ---------------- S2b: exclusive scan over NB bucket totals ----------------
__global__ __launch_bounds__(1024) void s_scanB(
    const unsigned* __restrict__ T, unsigned* __restrict__ basep,
    unsigned* __restrict__ rs, int N)
{
    __shared__ unsigned sc[NB];
    const int t = threadIdx.x;
    unsigned my = T[t];
    sc[t] = my;
    __syncthreads();
    for (int off = 1; off < NB; off <<= 1) {
        unsigned a = (t >= off) ? sc[t - off] : 0u;
        __syncthreads();
        sc[t] += a;
        __syncthreads();
    }
    basep[t] = sc[t] - my;
    if (t == NB - 1) { basep[NB] = sc[t]; rs[N] = sc[t]; }
}

// ---------------- S3: scatter into coarse-sorted records (LDS cursors only)
__global__ __launch_bounds__(256) void s_scatter3(
    const int* __restrict__ esrc, const int* __restrict__ edst,
    const float* __restrict__ ew, int E,
    const unsigned* __restrict__ basep, const unsigned* __restrict__ PT,
    uint2* __restrict__ recs)
{
    __shared__ unsigned cur[NB];
    const int blk = blockIdx.x;
    for (int i = threadIdx.x; i < NB; i += 256)
        cur[i] = basep[i] + PT[(size_t)blk * NB + i];
    __syncthreads();
    const int base = blk * CHK;
    int s[16], d[16]; float wv[16];
    #pragma unroll
    for (int i = 0; i < 16; ++i) {
        int idx = base + i * 256 + threadIdx.x;
        const bool ok = (idx < E);
        s[i]  = ok ? esrc[idx] : 0;
        d[i]  = ok ? edst[idx] : 0;
        wv[i] = ok ? ew[idx]   : 0.0f;
        if (!ok || (s[i] & 3) == 0) d[i] = -1;   // pad or anchor-src: skip
    }
    #pragma unroll
    for (int i = 0; i < 16; ++i) {
        if (d[i] >= 0) {
            const unsigned slot = atomicAdd(&cur[((unsigned)d[i]) >> 8], 1u);
            const unsigned pack =
                ((unsigned)s[i]) | ((((unsigned)d[i]) & 255u) << 18);
            recs[slot] = make_uint2(pack, __float_as_uint(wv[i]));
        }
    }
}

// ---------------- S4: per-bucket fine sort -> 4B records -------------------
// output record: src (bits 0..17) | wq (bits 18..31), wq = round(w * 16384)
__global__ __launch_bounds__(256) void s_sortfine(
    const uint2* __restrict__ recs, const unsigned* __restrict__ basep,
    unsigned* __restrict__ recf, unsigned* __restrict__ rs)
{
    __shared__ unsigned hist[RB], sc[RB], cur[RB];
    const int t = threadIdx.x;
    const int b = blockIdx.x;
    const unsigned start = basep[b], end = basep[b + 1];
    hist[t] = 0;
    __syncthreads();
    for (unsigned i = start + t; i < end; i += 256)
        atomicAdd(&hist[recs[i].x >> 18], 1u);
    __syncthreads();
    sc[t] = hist[t];
    __syncthreads();
    for (int off = 1; off < RB; off <<= 1) {
        unsigned v = (t >= off) ? sc[t - off] : 0u;
        __syncthreads();
        sc[t] += v;
        __syncthreads();
    }
    const unsigned excl = sc[t] - hist[t];
    cur[t] = start + excl;
    rs[b * RB + t] = start + excl;
    __syncthreads();
    for (unsigned i = start + t; i < end; i += 256) {
        uint2 r = recs[i];
        unsigned slot = atomicAdd(&cur[r.x >> 18], 1u);
        unsigned wq = (unsigned)(__uint_as_float(r.y) * WQS + 0.5f);
        wq = min(wq, 16383u);
        recf[slot] = (r.x & 0x3FFFFu) | (wq << 18);
    }
}

// ---------------- S5: one wave per dst row, register accumulation ----------
// lean: no LDS, minimal VGPR -> max occupancy for the latency-bound gather.
// 4B records: 1 readlane/edge; integer weights accumulated, scaled once/row.
__global__ __launch_bounds__(256) void s_accum4(
    const float* __restrict__ in_feat, const unsigned* __restrict__ recf,
    const unsigned* __restrict__ rs, float* __restrict__ h,
    int NROWS, int totalWaves)
{
    const int lane = threadIdx.x & 63;
    const int wid = (int)((blockIdx.x * (size_t)blockDim.x + threadIdx.x) >> 6);

    for (int row = wid; row < NROWS; row += totalWaves) {
        const unsigned s = rs[row], e = rs[row + 1];
        float acc = 0.0f;
        unsigned done = s;
        while (done < e) {
            const int c = (int)min(64u, e - done);
            unsigned rcd = 0u;
            if (lane < c) rcd = recf[done + lane];   // coalesced 4B x c
            for (int j0 = 0; j0 < c; j0 += GU) {
                float v[GU], wj[GU];
                #pragma unroll
                for (int jj = 0; jj < GU; ++jj) {
                    const int idx = j0 + jj;
                    const int cl  = (idx < c) ? idx : (c - 1);
                    const unsigned px =
                        (unsigned)__builtin_amdgcn_readlane((int)rcd, cl);
                    v[jj]  = in_feat[((size_t)(px & 0x3FFFFu) << 6) + lane];
                    wj[jj] = (idx < c) ? (float)(px >> 18) : 0.0f;
                }
                #pragma unroll
                for (int jj = 0; jj < GU; ++jj) acc = fmaf(v[jj], wj[jj], acc);
            }
            done += (unsigned)c;
        }
        h[((size_t)row << 6) + lane] = acc * (1.0f / WQS);
    }
}

// ---------------- fallback K2 (atomic scatter) ----------------------------
#define K2_U 8
__global__ __launch_bounds__(256) void k_edges(
    const float* __restrict__ in_feat, const int* __restrict__ esrc,
    const int* __restrict__ edst, const float* __restrict__ ew,
    float* __restrict__ h, int E, int totalWaves)
{
    const int lane = threadIdx.x & 63;
    int wid = (int)((blockIdx.x * (size_t)blockDim.x + threadIdx.x) >> 6);
    wid = __builtin_amdgcn_readfirstlane(wid);
    const int chunk = (E + totalWaves - 1) / totalWaves;
    int e0 = wid * chunk;
    int e1 = min(e0 + chunk, E);
    for (int base = e0; base < e1; base += K2_U) {
        const int nb = min(K2_U, e1 - base);
        int s[K2_U], d[K2_U]; float w[K2_U];
        #pragma unroll
        for (int j = 0; j < K2_U; ++j) {
            int idx = base + ((j < nb) ? j : 0);
            s[j] = esrc[idx]; d[j] = edst[idx]; w[j] = ew[idx];
        }
        float v[K2_U];
        #pragma unroll
        for (int j = 0; j < K2_U; ++j)
            v[j] = in_feat[((size_t)s[j] << 6) + lane];
        #pragma unroll
        for (int j = 0; j < K2_U; ++j)
            if (j < nb) atomicAdd(h + ((size_t)d[j] << 6) + lane, v[j] * w[j]);
    }
}

// ---------------- K3: activation + pool + two GEMVs + l2norm --------------
__global__ __launch_bounds__(256) void k_finalize(
    const float* __restrict__ h, const float* __restrict__ bias,
    const float* __restrict__ prelu_a,
    const float* __restrict__ w_sub, const float* __restrict__ b_sub,
    const float* __restrict__ w_gcn, const float* __restrict__ b_gcn,
    float* __restrict__ out_sub, float* __restrict__ out_gcn,
    int G, int totalWaves)
{
    const int lane = threadIdx.x & 63;
    const int wid = (int)((blockIdx.x * (size_t)blockDim.x + threadIdx.x) >> 6);

    float wsreg[64], wgreg[64];
    #pragma unroll
    for (int k = 0; k < 64; ++k) wsreg[k] = w_sub[lane * 64 + k];
    #pragma unroll
    for (int k = 0; k < 64; ++k) wgreg[k] = w_gcn[lane * 64 + k];
    const float bj  = bias[lane];
    const float bsj = b_sub[lane];
    const float bgj = b_gcn[lane];
    const float a   = prelu_a[0];

    for (int g = wid; g < G; g += totalWaves) {
        const float* hp = h + (size_t)g * 256;
        float p0 = preluf(hp[lane]       + bj, a);
        float p1 = preluf(hp[64  + lane] + bj, a);
        float p2 = preluf(hp[128 + lane] + bj, a);
        float p3 = preluf(hp[192 + lane] + bj, a);
        float pool = (p0 + p1 + p2 + p3) * 0.25f;
        float gcn  = p0;

        float as = bsj, ag = bgj;
        #pragma unroll
        for (int k = 0; k < 64; ++k) {
            as = fmaf(rdlane(pool, k), wsreg[k], as);
            ag = fmaf(rdlane(gcn,  k), wgreg[k], ag);
        }
        float ss = as * as, sg = ag * ag;
        #pragma unroll
        for (int off = 32; off >= 1; off >>= 1) {
            ss += __shfl_xor(ss, off, 64);
            sg += __shfl_xor(sg, off, 64);
        }
        out_sub[(size_t)g * 64 + lane] = as / fmaxf(sqrtf(ss), EPSN);
        out_gcn[(size_t)g * 64 + lane] = ag / fmaxf(sqrtf(sg), EPSN);
    }
}

extern "C" void kernel_launch(void* const* d_in, const int* in_sizes, int n_in,
                              void* d_out, int out_size, void* d_ws, size_t ws_size,
                              hipStream_t stream)
{
    const float* feat    = (const float*)d_in[0];
    const int*   esrc    = (const int*)  d_in[1];
    const int*   edst    = (const int*)  d_in[2];
    const float* ew      = (const float*)d_in[3];
    const float* weight  = (const float*)d_in[4];
    const float* bias    = (const float*)d_in[5];
    const float* prelu_a = (const float*)d_in[6];
    const float* w_sub   = (const float*)d_in[7];
    const float* b_sub   = (const float*)d_in[8];
    const float* w_gcn   = (const float*)d_in[9];
    const float* b_gcn   = (const float*)d_in[10];

    const int N = in_sizes[0] / 128;
    const int E = in_sizes[1];
    const int G = N / 4;
    const int nwg = (E + CHK - 1) / CHK;

    // ws layout (sorted path; bytes). A = N*64*4 = 67.1 MB:
    //   in_feat : [0, A)
    //   h       : [A, 2A)        -- written by s_accum4 (after sortfine)
    //   recs    : [A, A+E*8)     -- overlays h; dead before s_accum4 runs
    //   recf    : [2A, 2A+E*4)
    //   C       : [.., +nwg*NB*4)   (scanned IN PLACE; doubles as PT)
    //   T       : NB*4
    //   basep   : (NB+1)*4
    //   rs      : (N+1)*4
    char* wsb = (char*)d_ws;
    const size_t A     = (size_t)N * 64 * 4;
    const size_t offRf = 2 * A;
    const size_t offC  = offRf + (size_t)E * 4;
    const size_t offT  = offC  + (size_t)nwg * NB * 4;
    const size_t offBp = offT  + (size_t)NB * 4;
    const size_t offRs = offBp + (size_t)(NB + 1) * 4;
    const size_t ws_need = offRs + (size_t)(N + 1) * 4;

    float*    in_feat = (float*)wsb;
    float*    h       = (float*)(wsb + A);
    uint2*    recs    = (uint2*)(wsb + A);
    unsigned* recf    = (unsigned*)(wsb + offRf);
    unsigned* C       = (unsigned*)(wsb + offC);
    unsigned* T       = (unsigned*)(wsb + offT);
    unsigned* basep   = (unsigned*)(wsb + offBp);
    unsigned* rs      = (unsigned*)(wsb + offRs);

    float* out        = (float*)d_out;
    float* out_sub    = out;
    float* out_anchor = out + (size_t)G * 64;
    float* out_gcn    = out + (size_t)2 * G * 64;

    const bool sorted_path =
        (N == NB * RB) && (nwg <= NWGMAX) && (ws_size >= ws_need);

    {   // K1
        const int blocks = 2048, tw = blocks * 4;
        k_transform<<<blocks, 256, 0, stream>>>(feat, weight, bias, prelu_a,
                                                in_feat, out_anchor, N, tw);
    }

    if (sorted_path) {
        s_count2  <<<nwg, 256, 0, stream>>>(esrc, edst, E, C);
        s_scanA   <<<NB, 256, 0, stream>>>(C, T, nwg);
        s_scanB   <<<1, 1024, 0, stream>>>(T, basep, rs, N);
        s_scatter3<<<nwg, 256, 0, stream>>>(esrc, edst, ew, E, basep, C, recs);
        s_sortfine<<<NB, 256, 0, stream>>>(recs, basep, recf, rs);
        {
            const int blocks = 2048, tw = blocks * 4;   // 8192 waves, 32 rows each
            s_accum4<<<blocks, 256, 0, stream>>>(in_feat, recf, rs, h, N, tw);
        }
        {
            const int blocks = 4096, tw = blocks * 4;
            k_finalize<<<blocks, 256, 0, stream>>>(h, bias, prelu_a, w_sub, b_sub,
                                                   w_gcn, b_gcn, out_sub, out_gcn, G, tw);
        }
    } else if (ws_size >= 2 * A) {
        hipMemsetAsync(h, 0, A, stream);
        const int blocks = 2048, tw = blocks * 4;
        k_edges<<<blocks, 256, 0, stream>>>(in_feat, esrc, edst, ew, h, E, tw);
        const int fblocks = 4096, ftw = fblocks * 4;
        k_finalize<<<fblocks, 256, 0, stream>>>(h, bias, prelu_a, w_sub, b_sub,
                                                w_gcn, b_gcn, out_sub, out_gcn, G, ftw);
    }
}